// Round 2
// baseline (412.880 us; speedup 1.0000x reference)
//
#include <hip/hip_runtime.h>
#include <hip/hip_fp16.h>

// Problem constants (fixed by the reference):
//   B=32768, N=4, F_IN=512, D=64  -> GEMM [131072 x 512] x [512 x 192]
#define BTOT   32768
#define FIN    512
#define NCOLS  192       // packed k|q|v output columns
#define KSTEPS 16        // 512 / 32
#define NTILES 12        // 192 / 16
// Swizzled weight buffer: [KSTEPS][NTILES][64 lanes][8 halves] = 98304 halves
#define WH_ELEMS (KSTEPS * NTILES * 64 * 8)
#define CHUNK_HALVES (NTILES * 64 * 8)   // 6144 halves = 12288 B per k-step

using half8   = __attribute__((ext_vector_type(8))) _Float16;
using floatx4 = __attribute__((ext_vector_type(4))) float;

// Convert Wk|Wq|Wv (fp32 [512,64] each) into fp16 MFMA B-fragment order.
// B-operand layout for mfma_f32_16x16x32_f16: lane holds B[k=(lane>>4)*8+j][n=lane&15].
__global__ void convert_w_kernel(const float* __restrict__ Wk,
                                 const float* __restrict__ Wq,
                                 const float* __restrict__ Wv,
                                 _Float16* __restrict__ Wh) {
    int idx = blockIdx.x * blockDim.x + threadIdx.x;
    if (idx >= WH_ELEMS) return;
    int j    = idx & 7;
    int lane = (idx >> 3) & 63;
    int t    = (idx >> 9) % NTILES;
    int kk   = idx / CHUNK_HALVES;
    int k = kk * 32 + (lane >> 4) * 8 + j;
    int n = t * 16 + (lane & 15);
    const float* src = (n < 64) ? Wk : (n < 128) ? Wq : Wv;
    Wh[idx] = (_Float16)src[k * 64 + (n & 63)];
}

// Fused projection-GEMM + tiny attention + maxpool.
// Wave = 16 drug rows (4 b's); WG = 4 waves = 16 b's; grid = 2048 WGs.
// No LDS, no barriers: B-fragments load straight from global (192 KB total,
// one 12 KB chunk fits L1; all waves on a CU reuse it -> L1/L2 hits).
// A-fragments load straight from the fp32 drug rows (full-line utilization)
// and convert to fp16 in-register.
__global__ __launch_bounds__(256, 4) void attn_fused_kernel(
        const float* __restrict__ drug,    // [131072, 512] fp32
        const _Float16* __restrict__ Wh,   // swizzled fp16 weights
        float* __restrict__ out)           // [32768, 64] fp32
{
    const int tid  = threadIdx.x;
    const int wave = tid >> 6;
    const int lane = tid & 63;
    const int quad = lane >> 4;   // A-frag k-subgroup; also b-index in epilogue
    const int l15  = lane & 15;   // A-frag row m; C/D column

    // This lane's A row: m = l15 within the wave's 16-row block.
    const int row = blockIdx.x * 64 + wave * 16 + l15;
    const float* arow = drug + (size_t)row * FIN + quad * 8;
    // This lane's B-fragment base: 16 B per lane, stride 16 B across lanes
    // -> each ds/global load below is a fully-coalesced 1 KB wave access.
    const half8* bbase = (const half8*)(Wh + lane * 8);

    floatx4 acc[NTILES];
#pragma unroll
    for (int t = 0; t < NTILES; ++t) acc[t] = (floatx4){0.f, 0.f, 0.f, 0.f};

    for (int kk = 0; kk < KSTEPS; ++kk) {
        // --- load A fragment: 8 consecutive fp32, convert to fp16 ---
        const float4* ap = (const float4*)(arow + kk * 32);
        float4 a0 = ap[0];
        float4 a1 = ap[1];

        const half8* bp = bbase + kk * (CHUNK_HALVES / 8);

        half8 afrag;
        afrag[0] = (_Float16)a0.x; afrag[1] = (_Float16)a0.y;
        afrag[2] = (_Float16)a0.z; afrag[3] = (_Float16)a0.w;
        afrag[4] = (_Float16)a1.x; afrag[5] = (_Float16)a1.y;
        afrag[6] = (_Float16)a1.z; afrag[7] = (_Float16)a1.w;

#pragma unroll
        for (int t = 0; t < NTILES; ++t) {
            half8 bfrag = bp[t * 64];   // (t*64+lane)*8 halves from chunk base
            acc[t] = __builtin_amdgcn_mfma_f32_16x16x32_f16(afrag, bfrag, acc[t], 0, 0, 0);
        }
    }

    // ---- epilogue: per-quad attention over its b ----
    // acc[t] reg r holds C[row = quad*4 + r][col = t*16 + l15]:
    //   tiles 0-3 = k (d = t*16+l15), 4-7 = q, 8-11 = v.
    // quad q's 16 lanes hold all 64 d's for b_local = q, n = reg.
    float p[4][4];
#pragma unroll
    for (int n = 0; n < 4; ++n)
#pragma unroll
        for (int m = 0; m < 4; ++m) {
            float s = 0.f;
#pragma unroll
            for (int t = 0; t < 4; ++t) s += acc[t][n] * acc[4 + t][m];
            p[n][m] = s;
        }

    // reduce the d-dimension across the 16 lanes of this quad
#pragma unroll
    for (int mask = 1; mask < 16; mask <<= 1) {
#pragma unroll
        for (int n = 0; n < 4; ++n)
#pragma unroll
            for (int m = 0; m < 4; ++m)
                p[n][m] += __shfl_xor(p[n][m], mask, 64);
    }

    // softmax over m (no 1/sqrt(d) scaling, matching reference), PV, maxpool over n
    float res[4] = {-INFINITY, -INFINITY, -INFINITY, -INFINITY};
#pragma unroll
    for (int n = 0; n < 4; ++n) {
        float mx = fmaxf(fmaxf(p[n][0], p[n][1]), fmaxf(p[n][2], p[n][3]));
        float e0 = __expf(p[n][0] - mx);
        float e1 = __expf(p[n][1] - mx);
        float e2 = __expf(p[n][2] - mx);
        float e3 = __expf(p[n][3] - mx);
        float inv = 1.f / (e0 + e1 + e2 + e3);
#pragma unroll
        for (int t = 0; t < 4; ++t) {
            float o = (e0 * acc[8 + t][0] + e1 * acc[8 + t][1] +
                       e2 * acc[8 + t][2] + e3 * acc[8 + t][3]) * inv;
            res[t] = fmaxf(res[t], o);
        }
    }

    const int b = blockIdx.x * 16 + wave * 4 + quad;
#pragma unroll
    for (int t = 0; t < 4; ++t)
        out[b * 64 + t * 16 + l15] = res[t];
}

extern "C" void kernel_launch(void* const* d_in, const int* in_sizes, int n_in,
                              void* d_out, int out_size, void* d_ws, size_t ws_size,
                              hipStream_t stream) {
    const float* drug = (const float*)d_in[0];
    const float* Wk   = (const float*)d_in[1];
    const float* Wq   = (const float*)d_in[2];
    const float* Wv   = (const float*)d_in[3];
    float* out = (float*)d_out;
    _Float16* Wh = (_Float16*)d_ws;   // 196608 B of scratch

    convert_w_kernel<<<(WH_ELEMS + 255) / 256, 256, 0, stream>>>(Wk, Wq, Wv, Wh);
    attn_fused_kernel<<<BTOT / 16, 256, 0, stream>>>(drug, Wh, out);
}

// Round 3
// 367.010 us; speedup vs baseline: 1.1250x; 1.1250x over previous
//
#include <hip/hip_runtime.h>
#include <hip/hip_fp16.h>

// Problem constants (fixed by the reference):
//   B=32768, N=4, F_IN=512, D=64  -> GEMM [131072 x 512] x [512 x 192]
#define BTOT   32768
#define FIN    512
#define NCOLS  192       // packed k|q|v output columns
#define KSTEPS 16        // 512 / 32
#define NTILES 12        // 192 / 16
// Swizzled weight buffer: [KSTEPS][NTILES][64 lanes][8 halves] = 98304 halves
#define WH_ELEMS (KSTEPS * NTILES * 64 * 8)
#define CHUNK_HALVES (NTILES * 64 * 8)   // 6144 halves = 12288 B per k-step
#define CHUNK_BYTES  (CHUNK_HALVES * 2)
#define PHASES 8                          // 2 k-steps staged per phase

using half8   = __attribute__((ext_vector_type(8))) _Float16;
using floatx4 = __attribute__((ext_vector_type(4))) float;

// Async global->LDS, 16 B per lane. LDS dest is wave-uniform base + lane*16.
#define GLOAD_LDS16(gp, lp)                                                  \
    __builtin_amdgcn_global_load_lds(                                        \
        (const __attribute__((address_space(1))) void*)(gp),                 \
        (__attribute__((address_space(3))) void*)(lp), 16, 0, 0)

// Convert Wk|Wq|Wv (fp32 [512,64] each) into fp16 MFMA B-fragment order.
// B-operand layout for mfma_f32_16x16x32_f16: lane holds B[k=(lane>>4)*8+j][n=lane&15].
__global__ void convert_w_kernel(const float* __restrict__ Wk,
                                 const float* __restrict__ Wq,
                                 const float* __restrict__ Wv,
                                 _Float16* __restrict__ Wh) {
    int idx = blockIdx.x * blockDim.x + threadIdx.x;
    if (idx >= WH_ELEMS) return;
    int j    = idx & 7;
    int lane = (idx >> 3) & 63;
    int t    = (idx >> 9) % NTILES;
    int kk   = idx / CHUNK_HALVES;
    int k = kk * 32 + (lane >> 4) * 8 + j;
    int n = t * 16 + (lane & 15);
    const float* src = (n < 64) ? Wk : (n < 128) ? Wq : Wv;
    Wh[idx] = (_Float16)src[k * 64 + (n & 63)];
}

// Fused projection-GEMM + tiny attention + maxpool.
// Wave = 16 drug rows (4 b's); WG = 4 waves = 16 b's; grid = 2048 WGs.
// W staged via global_load_lds (width 16), 2 k-steps (24 KB) per phase:
// 16 barriers/block instead of 32, zero VGPR round-trip for staging.
__global__ __launch_bounds__(256) void attn_fused_kernel(
        const float* __restrict__ drug,    // [131072, 512] fp32
        const _Float16* __restrict__ Wh,   // swizzled fp16 weights
        float* __restrict__ out)           // [32768, 64] fp32
{
    __shared__ __align__(16) char lds[2 * CHUNK_BYTES];   // 24576 B

    const int tid  = threadIdx.x;
    const int wave = tid >> 6;
    const int lane = tid & 63;
    const int quad = lane >> 4;   // A-frag k-subgroup; also b-index in epilogue
    const int l15  = lane & 15;   // A-frag row m; C/D column

    // This lane's A row: m = l15 within the wave's 16-row block.
    const int row = blockIdx.x * 64 + wave * 16 + l15;
    const float* arow = drug + (size_t)row * FIN + quad * 8;
    const char* gW = (const char*)Wh;

    floatx4 acc[NTILES];
#pragma unroll
    for (int t = 0; t < NTILES; ++t) acc[t] = (floatx4){0.f, 0.f, 0.f, 0.f};

    for (int ph = 0; ph < PHASES; ++ph) {
        __syncthreads();   // prior phase's LDS reads complete before overwrite

        // --- stage 2 W chunks (24576 B) via async global->LDS ---
        // 1536 lane-transfers of 16 B; 6 instructions x (4 waves x 64 lanes).
        const size_t goff = (size_t)ph * 2 * CHUNK_BYTES;
#pragma unroll
        for (int i = 0; i < 6; ++i) {
            const int off = i * 4096 + wave * 1024;   // wave-uniform LDS base
            GLOAD_LDS16(gW + goff + off + lane * 16, lds + off);
        }

        // --- load A fragments for both k-steps (overlaps staging) ---
        const float4* ap0 = (const float4*)(arow + (2 * ph) * 32);
        const float4* ap1 = (const float4*)(arow + (2 * ph + 1) * 32);
        float4 a00 = ap0[0], a01 = ap0[1];
        float4 a10 = ap1[0], a11 = ap1[1];

        half8 afrag[2];
        afrag[0][0] = (_Float16)a00.x; afrag[0][1] = (_Float16)a00.y;
        afrag[0][2] = (_Float16)a00.z; afrag[0][3] = (_Float16)a00.w;
        afrag[0][4] = (_Float16)a01.x; afrag[0][5] = (_Float16)a01.y;
        afrag[0][6] = (_Float16)a01.z; afrag[0][7] = (_Float16)a01.w;
        afrag[1][0] = (_Float16)a10.x; afrag[1][1] = (_Float16)a10.y;
        afrag[1][2] = (_Float16)a10.z; afrag[1][3] = (_Float16)a10.w;
        afrag[1][4] = (_Float16)a11.x; afrag[1][5] = (_Float16)a11.y;
        afrag[1][6] = (_Float16)a11.z; afrag[1][7] = (_Float16)a11.w;

        __syncthreads();   // staged chunks visible

#pragma unroll
        for (int s = 0; s < 2; ++s) {
            const _Float16* lh = (const _Float16*)(lds + s * CHUNK_BYTES);
#pragma unroll
            for (int t = 0; t < NTILES; ++t) {
                half8 bfrag = *((const half8*)(lh + (t * 64 + lane) * 8));
                acc[t] = __builtin_amdgcn_mfma_f32_16x16x32_f16(afrag[s], bfrag, acc[t], 0, 0, 0);
            }
        }
    }

    // ---- epilogue: per-quad attention over its b ----
    // acc[t] reg r holds C[row = quad*4 + r][col = t*16 + l15]:
    //   tiles 0-3 = k (d = t*16+l15), 4-7 = q, 8-11 = v.
    // quad q's 16 lanes hold all 64 d's for b_local = q, n = reg.
    float p[4][4];
#pragma unroll
    for (int n = 0; n < 4; ++n)
#pragma unroll
        for (int m = 0; m < 4; ++m) {
            float s = 0.f;
#pragma unroll
            for (int t = 0; t < 4; ++t) s += acc[t][n] * acc[4 + t][m];
            p[n][m] = s;
        }

    // reduce the d-dimension across the 16 lanes of this quad
#pragma unroll
    for (int mask = 1; mask < 16; mask <<= 1) {
#pragma unroll
        for (int n = 0; n < 4; ++n)
#pragma unroll
            for (int m = 0; m < 4; ++m)
                p[n][m] += __shfl_xor(p[n][m], mask, 64);
    }

    // softmax over m (no 1/sqrt(d) scaling, matching reference), PV, maxpool over n
    float res[4] = {-INFINITY, -INFINITY, -INFINITY, -INFINITY};
#pragma unroll
    for (int n = 0; n < 4; ++n) {
        float mx = fmaxf(fmaxf(p[n][0], p[n][1]), fmaxf(p[n][2], p[n][3]));
        float e0 = __expf(p[n][0] - mx);
        float e1 = __expf(p[n][1] - mx);
        float e2 = __expf(p[n][2] - mx);
        float e3 = __expf(p[n][3] - mx);
        float inv = 1.f / (e0 + e1 + e2 + e3);
#pragma unroll
        for (int t = 0; t < 4; ++t) {
            float o = (e0 * acc[8 + t][0] + e1 * acc[8 + t][1] +
                       e2 * acc[8 + t][2] + e3 * acc[8 + t][3]) * inv;
            res[t] = fmaxf(res[t], o);
        }
    }

    const int b = blockIdx.x * 16 + wave * 4 + quad;
#pragma unroll
    for (int t = 0; t < 4; ++t)
        out[b * 64 + t * 16 + l15] = res[t];
}

extern "C" void kernel_launch(void* const* d_in, const int* in_sizes, int n_in,
                              void* d_out, int out_size, void* d_ws, size_t ws_size,
                              hipStream_t stream) {
    const float* drug = (const float*)d_in[0];
    const float* Wk   = (const float*)d_in[1];
    const float* Wq   = (const float*)d_in[2];
    const float* Wv   = (const float*)d_in[3];
    float* out = (float*)d_out;
    _Float16* Wh = (_Float16*)d_ws;   // 196608 B of scratch

    convert_w_kernel<<<(WH_ELEMS + 255) / 256, 256, 0, stream>>>(Wk, Wq, Wv, Wh);
    attn_fused_kernel<<<BTOT / 16, 256, 0, stream>>>(drug, Wh, out);
}